// Round 17
// baseline (245.791 us; speedup 1.0000x reference)
//
#include <hip/hip_runtime.h>

// AxisAttention: x(8,256,128,128) -> per (b,w) sequence over h: QKV GEMM, 4-head
// attention (S=128, d=64), proj GEMM, transposed fp32 output.
// All matmuls: v_mfma_f32_16x16x32_f16, fp32 accum.
// v17 = v16 with the k1f epilogue store FIXED: each thread must write 32 fp16
//   (dhs stride 32) but v16 emitted only 2 u4 stores (16 fp16) -> d[16,32) and
//   d[48,64) stale -> absmax 1.17. Now 4 u4 stores. Everything else identical:
//  - k1f block (bl, hb): all 128 w, all 768 f; A-panel (64KB) staged once per
//    ft (chunk-XOR swizzle, rule-21 verified); 128 MFMA barrier-free per ft.
//  - k2/k3/prep_w byte-identical to v15 (proven).

typedef _Float16 h4 __attribute__((ext_vector_type(4)));
typedef _Float16 h8 __attribute__((ext_vector_type(8)));
typedef float f4 __attribute__((ext_vector_type(4)));
typedef unsigned int u4 __attribute__((ext_vector_type(4)));

#define MFMA32(a, b, c) __builtin_amdgcn_mfma_f32_16x16x32_f16((a), (b), (c), 0, 0, 0)

__device__ __forceinline__ void gll16(const _Float16* g, _Float16* l) {
  __builtin_amdgcn_global_load_lds(
      (const __attribute__((address_space(1))) void*)g,
      (__attribute__((address_space(3))) void*)l, 16, 0, 0);
}

// ---------------- prep: W^T fp16 (wqt[f][c], wpt[f][c]) ----------------
__global__ __launch_bounds__(256) void prep_w(const float* __restrict__ Wqkv,
                                              const float* __restrict__ Wproj,
                                              _Float16* __restrict__ wqt,
                                              _Float16* __restrict__ wpt) {
  int i = blockIdx.x * 256 + threadIdx.x;  // 196608 + 65536
  if (i < 768 * 256) {
    int f = i >> 8, c = i & 255;
    wqt[i] = (_Float16)Wqkv[c * 768 + f];
  } else {
    int j = i - 768 * 256;
    int f = j >> 8, c = j & 255;
    wpt[j] = (_Float16)Wproj[c * 256 + f];
  }
}

// ---------------- K1F: fused x-transpose + QKV GEMM (wide block) ----------------
// Block (bl, hb): tokens t = w 0..127 at fixed h=hb; computes all 768 f.
// Phase 0: coalesced x reads -> sXT[128 w][264 c] fp16.
// Phase 1: each wave preloads B-frags for its t-quarter (K=256) into 64 VGPRs.
// Main: per ft stage whole A-panel [128 f][256 c] (64KB, chunk-XOR swizzle),
//       then 64 ds_read + 128 MFMA barrier-free.
// qkv layout: [qi*nb+bl][head][h][w][d]
__global__ __launch_bounds__(256, 2) void k1f(const float* __restrict__ x,
                                              const _Float16* __restrict__ wqt,
                                              const float* __restrict__ bqkv,
                                              _Float16* __restrict__ qkv,
                                              int b_base, int nb) {
  const int wg = blockIdx.x;
  const int xcd = wg & 7, seq = wg >> 3;
  const int id = xcd * (nb * 16) + seq;  // bijective: grid = nb*128, %8 == 0
  const int hb = id & 127;
  const int bl = id >> 7;
  const int b = b_base + bl;

  const int tid = threadIdx.x;
  const int lane = tid & 63, wv = tid >> 6;
  const int g = lane >> 4, l16 = lane & 15;

  __shared__ __align__(16) char smem[67584];
  _Float16* sXT = (_Float16*)smem;  // [128 w][264 c] 67584 B (phase 0-1 ONLY)
  _Float16* sA = (_Float16*)smem;   // [128 f][256 c] 65536 B (aliases sXT)
  _Float16* sO = (_Float16*)smem;   // [128 t][136 f] 34816 B (aliases sA post-MFMA)

  // ---- phase 0: transpose x[b][c][hb][0..127] -> sXT[w][c] (fp16) ----
  {
    const int j0 = tid & 15, r16 = tid >> 4;  // 16 lanes x 16B = 256B runs
#pragma unroll
    for (int p = 0; p < 16; ++p) {
      const int c = p * 16 + r16;
      const float* src = x + (((long)b * 256 + c) * 128 + hb) * 128;
      f4 v0 = *(const f4*)(src + j0 * 4);
      f4 v1 = *(const f4*)(src + (j0 + 16) * 4);
#pragma unroll
      for (int i = 0; i < 4; ++i) {
        sXT[(j0 * 4 + i) * 264 + c] = (_Float16)v0[i];
        sXT[((j0 + 16) * 4 + i) * 264 + c] = (_Float16)v1[i];
      }
    }
  }
  __syncthreads();

  // ---- phase 1: preload B-fragments for this wave's t-quarter ----
  h8 bfr[4][2][2];  // [kc][ks][nt]
#pragma unroll
  for (int kc = 0; kc < 4; ++kc)
#pragma unroll
    for (int ks = 0; ks < 2; ++ks)
#pragma unroll
      for (int nt = 0; nt < 2; ++nt) {
        const int t = wv * 32 + nt * 16 + l16;
        bfr[kc][ks][nt] =
            *(const h8*)(sXT + t * 264 + kc * 64 + ks * 32 + 8 * g);
      }
  __syncthreads();  // sXT dead; sA/sO may now overwrite it

  const int srow2 = wv * 32;          // wave's A-staging row base (32 rows)
  const int c5 = lane & 31, r2 = lane >> 5;
  const int wl = tid >> 1, dhs = (tid & 1) * 32;

  // ---- main loop over 6 f-tiles of 128 ----
  for (int ft = 0; ft < 6; ++ft) {
    const int f0 = ft * 128;
    f4 acc[8][2];
#pragma unroll
    for (int mt = 0; mt < 8; ++mt)
#pragma unroll
      for (int nt = 0; nt < 2; ++nt)
#pragma unroll
        for (int r = 0; r < 4; ++r) acc[mt][nt][r] = 0.f;

    // stage whole A-panel [128 f][256 c], chunk-XOR swizzled source.
#pragma unroll
    for (int i = 0; i < 16; ++i) {
      const int row = srow2 + i * 2 + r2;
      const int sch = c5 ^ (row & 7);
      gll16(wqt + (long)(f0 + row) * 256 + sch * 8, sA + (srow2 + i * 2) * 256);
    }
    __syncthreads();

    // barrier-free MFMA nest: 64 ds_read + 128 MFMA per wave
#pragma unroll
    for (int kc = 0; kc < 4; ++kc)
#pragma unroll
      for (int ks = 0; ks < 2; ++ks) {
        h8 af[8];
#pragma unroll
        for (int mt = 0; mt < 8; ++mt) {
          const int row = mt * 16 + l16;
          const int q = (kc * 8 + ks * 4 + g) ^ (l16 & 7);
          af[mt] = *(const h8*)(sA + row * 256 + q * 8);
        }
#pragma unroll
        for (int mt = 0; mt < 8; ++mt)
#pragma unroll
          for (int nt = 0; nt < 2; ++nt)
            acc[mt][nt] = MFMA32(af[mt], bfr[kc][ks][nt], acc[mt][nt]);
      }
    __syncthreads();  // all waves done with sA before sO overwrites

    // epilogue: bias + repack to sO[t][f_local 0..127]
#pragma unroll
    for (int mt = 0; mt < 8; ++mt) {
      f4 bb = *(const f4*)(bqkv + f0 + mt * 16 + 4 * g);
#pragma unroll
      for (int nt = 0; nt < 2; ++nt) {
        const int tl = wv * 32 + nt * 16 + l16;
#pragma unroll
        for (int r = 0; r < 4; ++r)
          sO[tl * 136 + mt * 16 + 4 * g + r] = (_Float16)(acc[mt][nt][r] + bb[r]);
      }
    }
    __syncthreads();
    // store: per (ft,h2) -> one (qi,head): 16KB contiguous at
    // qkv[(qi*nb+bl)*4+head][hb][w][d]; thread covers 32 fp16 (4 u4 stores)
#pragma unroll
    for (int h2 = 0; h2 < 2; ++h2) {
      const int fh = f0 + h2 * 64;
      const int qi = fh >> 8, head = (fh >> 6) & 3;
      _Float16* dst = qkv + (((long)(qi * nb + bl) * 4 + head) * 128 + hb) * 8192 +
                      wl * 64 + dhs;
      const _Float16* s = sO + wl * 136 + h2 * 64 + dhs;
#pragma unroll
      for (int e = 0; e < 4; ++e)
        *(u4*)(dst + e * 8) = *(const u4*)(s + e * 8);
    }
    __syncthreads();
  }
}

// ---------------- K2: attention per (w, head, bl) ---------------- (v15-proven)
__global__ __launch_bounds__(256) void k2_attn(const _Float16* __restrict__ qkv,
                                               _Float16* __restrict__ attnout,
                                               int nb) {
  const int w = blockIdx.x, head = blockIdx.y, bl = blockIdx.z;
  const int tid = threadIdx.x;
  const int lane = tid & 63, wv = tid >> 6;
  const int g = lane >> 4, l16 = lane & 15;

  __shared__ __align__(16) char smem[(128 * 72 * 2 + 64 * 136) * 2];  // 54272 B
  _Float16* sQ = (_Float16*)smem;
  _Float16* sK = sQ + 128 * 72;
  _Float16* sVT = sK + 128 * 72;
  _Float16* sP = sQ;
  _Float16* sO = sQ;

  const long base = (((long)bl * 4 + head) * 128) * 8192 + (long)w * 64;
  const long QS = (long)nb * 4 * 128 * 8192;
  const _Float16* qg = qkv + base;
  const _Float16* kg = qkv + base + QS;
  const _Float16* vg = qkv + base + 2 * QS;

#pragma unroll
  for (int i = 0; i < 4; ++i) {
    int u = tid + 256 * i;
    int hh = u >> 3, dq = u & 7;
    *(u4*)(sQ + hh * 72 + dq * 8) = *(const u4*)(qg + (long)hh * 8192 + dq * 8);
    *(u4*)(sK + hh * 72 + dq * 8) = *(const u4*)(kg + (long)hh * 8192 + dq * 8);
  }
  {
    const int hh = tid & 127, dcv = tid >> 7;
#pragma unroll
    for (int jj = 0; jj < 4; ++jj) {
      u4 vv = *(const u4*)(vg + (long)hh * 8192 + dcv * 32 + jj * 8);
      const _Float16* pe = (const _Float16*)&vv;
#pragma unroll
      for (int e = 0; e < 8; ++e)
        sVT[(dcv * 32 + jj * 8 + e) * 136 + hh] = pe[e];
    }
  }
  __syncthreads();

  f4 accS[8][2];
  for (int i = 0; i < 8; ++i)
    for (int jt = 0; jt < 2; ++jt)
      for (int r = 0; r < 4; ++r) accS[i][jt][r] = 0.f;
#pragma unroll
  for (int ks = 0; ks < 2; ++ks) {
    const int k = ks * 32 + 8 * g;
    h8 af[8], bf[2];
#pragma unroll
    for (int i = 0; i < 8; ++i)
      af[i] = *(const h8*)(sK + (i * 16 + l16) * 72 + k);
#pragma unroll
    for (int jt = 0; jt < 2; ++jt)
      bf[jt] = *(const h8*)(sQ + (wv * 32 + jt * 16 + l16) * 72 + k);
#pragma unroll
    for (int i = 0; i < 8; ++i)
#pragma unroll
      for (int jt = 0; jt < 2; ++jt)
        accS[i][jt] = MFMA32(af[i], bf[jt], accS[i][jt]);
  }

  float rinv[2];
#pragma unroll
  for (int jt = 0; jt < 2; ++jt) {
    float m = -1e30f;
    for (int i = 0; i < 8; ++i)
      for (int r = 0; r < 4; ++r) m = fmaxf(m, accS[i][jt][r]);
    m = fmaxf(m, __shfl_xor(m, 16));
    m = fmaxf(m, __shfl_xor(m, 32));
    float s = 0.f;
    for (int i = 0; i < 8; ++i)
      for (int r = 0; r < 4; ++r) {
        float p = __expf((accS[i][jt][r] - m) * 0.125f);
        accS[i][jt][r] = p;
        s += p;
      }
    s += __shfl_xor(s, 16);
    s += __shfl_xor(s, 32);
    rinv[jt] = 1.0f / s;
  }

  __syncthreads();
#pragma unroll
  for (int jt = 0; jt < 2; ++jt) {
    const int hq = wv * 32 + jt * 16 + l16;
#pragma unroll
    for (int i = 0; i < 8; ++i) {
      h4 pv;
      pv[0] = (_Float16)accS[i][jt][0];
      pv[1] = (_Float16)accS[i][jt][1];
      pv[2] = (_Float16)accS[i][jt][2];
      pv[3] = (_Float16)accS[i][jt][3];
      *(h4*)(sP + hq * 136 + i * 16 + 4 * g) = pv;
    }
  }
  __syncthreads();

  f4 accO[4][2];
  for (int mt = 0; mt < 4; ++mt)
    for (int jt = 0; jt < 2; ++jt)
      for (int r = 0; r < 4; ++r) accO[mt][jt][r] = 0.f;
#pragma unroll
  for (int i2 = 0; i2 < 4; ++i2) {
    const int k = i2 * 32 + 8 * g;
    h8 av[4], pb[2];
#pragma unroll
    for (int mt = 0; mt < 4; ++mt)
      av[mt] = *(const h8*)(sVT + (mt * 16 + l16) * 136 + k);
#pragma unroll
    for (int jt = 0; jt < 2; ++jt)
      pb[jt] = *(const h8*)(sP + (wv * 32 + jt * 16 + l16) * 136 + k);
#pragma unroll
    for (int mt = 0; mt < 4; ++mt)
#pragma unroll
      for (int jt = 0; jt < 2; ++jt)
        accO[mt][jt] = MFMA32(av[mt], pb[jt], accO[mt][jt]);
  }

  __syncthreads();
#pragma unroll
  for (int mt = 0; mt < 4; ++mt)
#pragma unroll
    for (int jt = 0; jt < 2; ++jt)
#pragma unroll
      for (int r = 0; r < 4; ++r)
        sO[(wv * 32 + jt * 16 + l16) * 72 + mt * 16 + 4 * g + r] =
            (_Float16)(accO[mt][jt][r] * rinv[jt]);
  __syncthreads();

  const int hh = tid >> 1, d0 = (tid & 1) * 32;
  const _Float16* s = sO + hh * 72 + d0;
  _Float16* dst = attnout + ((long)bl * 16384 + hh * 128 + w) * 256 + head * 64 + d0;
#pragma unroll
  for (int e = 0; e < 4; ++e)
    *(u4*)(dst + e * 8) = *(const u4*)(s + e * 8);
}

// ---------------- K3: out[b][co][t] = Wproj^T[co][c]*attnout[t][c]+bproj --------
// (v14-proven: swizzled A/B staging + reads)
__global__ __launch_bounds__(256, 4) void k3_proj(const _Float16* __restrict__ attnout,
                                                  const _Float16* __restrict__ wpt,
                                                  const float* __restrict__ bproj,
                                                  float* __restrict__ out,
                                                  int b_base, int nb) {
  const int ct = blockIdx.x, tt = blockIdx.y, bl = blockIdx.z;
  const int b = b_base + bl;
  const int tid = threadIdx.x;
  const int lane = tid & 63, wv = tid >> 6;
  const int g = lane >> 4, l16 = lane & 15;
  const int wr = wv >> 1, wc = wv & 1;
  const int co0 = ct * 128;
  const long t0 = (long)tt * 128;

  __shared__ __align__(16) char smem[33792];
  _Float16* sA = (_Float16*)smem;   // [128 co][64]
  _Float16* sB = sA + 128 * 64;     // [128 t][64]
  float* sOut = (float*)smem;       // reuse: [64][132] f32

  f4 acc[4][4];
#pragma unroll
  for (int mt = 0; mt < 4; ++mt)
#pragma unroll
    for (int nt = 0; nt < 4; ++nt)
#pragma unroll
      for (int r = 0; r < 4; ++r) acc[mt][nt][r] = 0.f;

  const _Float16* Ab = wpt + (long)co0 * 256;
  const _Float16* Bb = attnout + ((long)bl * 16384 + t0) * 256;
  const int r0 = wv * 32;
  const int rl = lane >> 3;
  const int chs = ((lane & 7) ^ rl) * 8;  // swizzled source chunk
  const int kx = (l16 & 7) * 8;           // read XOR

  for (int kc = 0; kc < 4; ++kc) {
    const int c0 = kc * 64;
#pragma unroll
    for (int i = 0; i < 4; ++i) {
      const int row = r0 + i * 8 + rl;
      gll16(Ab + (long)row * 256 + c0 + chs, sA + (r0 + i * 8) * 64);
      gll16(Bb + (long)row * 256 + c0 + chs, sB + (r0 + i * 8) * 64);
    }
    __syncthreads();
#pragma unroll
    for (int ks = 0; ks < 2; ++ks) {
      const int kk = (ks * 32 + 8 * g) ^ kx;
      h8 af[4], bf[4];
#pragma unroll
      for (int mt = 0; mt < 4; ++mt)
        af[mt] = *(const h8*)(sA + (wr * 64 + mt * 16 + l16) * 64 + kk);
#pragma unroll
      for (int nt = 0; nt < 4; ++nt)
        bf[nt] = *(const h8*)(sB + (wc * 64 + nt * 16 + l16) * 64 + kk);
#pragma unroll
      for (int mt = 0; mt < 4; ++mt)
#pragma unroll
        for (int nt = 0; nt < 4; ++nt)
          acc[mt][nt] = MFMA32(af[mt], bf[nt], acc[mt][nt]);
    }
    __syncthreads();
  }

#pragma unroll
  for (int h2 = 0; h2 < 2; ++h2) {
    if (h2) __syncthreads();
    if (wr == h2) {
#pragma unroll
      for (int mt = 0; mt < 4; ++mt) {
        f4 bb = *(const f4*)(bproj + co0 + h2 * 64 + mt * 16 + 4 * g);
#pragma unroll
        for (int nt = 0; nt < 4; ++nt)
#pragma unroll
          for (int r = 0; r < 4; ++r)
            sOut[(mt * 16 + 4 * g + r) * 132 + wc * 64 + nt * 16 + l16] =
                acc[mt][nt][r] + bb[r];
      }
    }
    __syncthreads();
    const int row = tid >> 2, seg = (tid & 3) * 32;
    const float* s = sOut + row * 132 + seg;
    float* dst = out + ((long)b * 256 + co0 + h2 * 64 + row) * 16384 + t0 + seg;
#pragma unroll
    for (int e = 0; e < 8; ++e)
      *(f4*)(dst + e * 4) = *(const f4*)(s + e * 4);
  }
}

// ---------------- launch ----------------
extern "C" void kernel_launch(void* const* d_in, const int* in_sizes, int n_in,
                              void* d_out, int out_size, void* d_ws, size_t ws_size,
                              hipStream_t stream) {
  const float* x = (const float*)d_in[0];
  const float* Wqkv = (const float*)d_in[1];
  const float* bqkv = (const float*)d_in[2];
  const float* Wproj = (const float*)d_in[3];
  const float* bproj = (const float*)d_in[4];
  float* out = (float*)d_out;

  char* ws = (char*)d_ws;
  // Layout: [wqt 384K][wpt 128K][qkv nb*24Mi][attnout nb*8Mi]
  const long WQT = 393216L, WPT = 131072L;
  const long PER_B = 25165824L + 8388608L;
  long nb_l = ((long)ws_size - (WQT + WPT)) / PER_B;
  int nb = nb_l < 1 ? 1 : (nb_l > 8 ? 8 : (int)nb_l);

  _Float16* wqt = (_Float16*)ws;
  _Float16* wpt = (_Float16*)(ws + WQT);
  _Float16* qkv = (_Float16*)(ws + WQT + WPT);
  _Float16* attnout = (_Float16*)(ws + WQT + WPT + (long)nb * 25165824L);

  prep_w<<<1024, 256, 0, stream>>>(Wqkv, Wproj, wqt, wpt);

  for (int b0 = 0; b0 < 8; b0 += nb) {
    int nbv = (8 - b0 < nb) ? (8 - b0) : nb;
    k1f<<<nbv * 128, 256, 0, stream>>>(x, wqt, bqkv, qkv, b0, nbv);
    k2_attn<<<dim3(128, 4, nbv), 256, 0, stream>>>(qkv, attnout, nbv);
    k3_proj<<<dim3(2, 128, nbv), 256, 0, stream>>>(attnout, wpt, bproj, out, b0, nbv);
  }
}

// Round 18
// 242.494 us; speedup vs baseline: 1.0136x; 1.0136x over previous
//
#include <hip/hip_runtime.h>

// AxisAttention: x(8,256,128,128) -> per (b,w) sequence over h: QKV GEMM, 4-head
// attention (S=128, d=64), proj GEMM, transposed fp32 output.
// All matmuls: v_mfma_f32_16x16x32_f16, fp32 accum.
// v18 = v15 with k1f's REGISTER PRESSURE fixed:
//   v15's k1f reported VGPR_Count=64 while holding bfr(64)+acc(32)+af(16)+addr
//   logically -> compiler was banking operands in AGPRs (unified file), adding
//   v_accvgpr round-trips per MFMA (the invariant ~140us across 7 structural
//   variants). Now: sXT kept ALIVE (disjoint from sA/sO, LDS 51200B, 3 blk/CU)
//   and bfr loaded per-kc (16 VGPR live) from persistent sXT. Live regs ~100.
// k2/k3/prep_w byte-identical to v15 (proven 244.2us).

typedef _Float16 h4 __attribute__((ext_vector_type(4)));
typedef _Float16 h8 __attribute__((ext_vector_type(8)));
typedef float f4 __attribute__((ext_vector_type(4)));
typedef unsigned int u4 __attribute__((ext_vector_type(4)));

#define MFMA32(a, b, c) __builtin_amdgcn_mfma_f32_16x16x32_f16((a), (b), (c), 0, 0, 0)

__device__ __forceinline__ void gll16(const _Float16* g, _Float16* l) {
  __builtin_amdgcn_global_load_lds(
      (const __attribute__((address_space(1))) void*)g,
      (__attribute__((address_space(3))) void*)l, 16, 0, 0);
}

// ---------------- prep: W^T fp16 (wqt[f][c], wpt[f][c]) ----------------
__global__ __launch_bounds__(256) void prep_w(const float* __restrict__ Wqkv,
                                              const float* __restrict__ Wproj,
                                              _Float16* __restrict__ wqt,
                                              _Float16* __restrict__ wpt) {
  int i = blockIdx.x * 256 + threadIdx.x;  // 196608 + 65536
  if (i < 768 * 256) {
    int f = i >> 8, c = i & 255;
    wqt[i] = (_Float16)Wqkv[c * 768 + f];
  } else {
    int j = i - 768 * 256;
    int f = j >> 8, c = j & 255;
    wpt[j] = (_Float16)Wproj[c * 256 + f];
  }
}

// ---------------- K1F: fused x-transpose + QKV GEMM ----------------
// Block (bl, hb, wh): tokens t = (w0..w0+63) at fixed h=hb; computes all 768 f.
// Phase 0: coalesced 128B x reads -> sXT[64t][264c] fp16 (PERSISTENT).
// Main: per (ft,kc): load 4 B-frags (16 VGPR) from sXT, stage A via gload_lds
//       (swizzled source, rule-21), 16 MFMA. sA/sO disjoint from sXT.
// qkv layout: [qi*nb+bl][head][h][w][d]
__global__ __launch_bounds__(256, 3) void k1f(const float* __restrict__ x,
                                              const _Float16* __restrict__ wqt,
                                              const float* __restrict__ bqkv,
                                              _Float16* __restrict__ qkv,
                                              int b_base, int nb) {
  const int wg = blockIdx.x;
  const int xcd = wg & 7, seq = wg >> 3;
  const int id = xcd * (nb * 32) + seq;  // bijective: grid = nb*256, %8 == 0
  const int hb = id & 127;
  const int rest = id >> 7;
  const int wh = rest & 1, bl = rest >> 1;
  const int b = b_base + bl;
  const int w0 = wh * 64;

  const int tid = threadIdx.x;
  const int lane = tid & 63, wv = tid >> 6;
  const int g = lane >> 4, l16 = lane & 15;
  const int wr = wv >> 1, wc = wv & 1;  // wave -> (f-half of 128, t-half of 64)

  __shared__ __align__(16) char smem[51200];
  _Float16* sXT = (_Float16*)smem;           // [64 t][264 c] 33792 B, PERSISTENT
  _Float16* sA = (_Float16*)(smem + 33792);  // [128 f][64 c] 16384 B
  _Float16* sO = (_Float16*)(smem + 33792);  // [64 t][136 f] 17408 B (aliases sA)

  // ---- phase 0: transpose x[b][c][hb][w0..w0+63] -> sXT[w][c] (fp16) ----
  {
    const int j0 = tid & 7, r8 = tid >> 3;  // 8 lanes x 16B = 128B coalesced
#pragma unroll
    for (int p = 0; p < 8; ++p) {
      const int c = p * 32 + r8;
      const float* src = x + (((long)b * 256 + c) * 128 + hb) * 128 + w0;
      f4 v0 = *(const f4*)(src + j0 * 4);
      f4 v1 = *(const f4*)(src + (j0 + 8) * 4);
#pragma unroll
      for (int i = 0; i < 4; ++i) {
        sXT[(j0 * 4 + i) * 264 + c] = (_Float16)v0[i];
        sXT[((j0 + 8) * 4 + i) * 264 + c] = (_Float16)v1[i];
      }
    }
  }
  __syncthreads();

  const int r0 = wv * 32;
  const int rl = lane >> 3;
  const int chs = ((lane & 7) ^ rl) * 8;  // swizzled source chunk (rule #21)
  const int wl = tid >> 2, dc = tid & 3;
  const int kx = (l16 & 7) * 8;           // per-lane read XOR (fp16 units)
  const int tB = wc * 32 + l16;           // B-frag token base (nt adds 16)

  // ---- main loop over 6 f-tiles of 128 ----
  for (int ft = 0; ft < 6; ++ft) {
    const int f0 = ft * 128;
    f4 acc[4][2];
#pragma unroll
    for (int mt = 0; mt < 4; ++mt)
#pragma unroll
      for (int nt = 0; nt < 2; ++nt)
#pragma unroll
        for (int r = 0; r < 4; ++r) acc[mt][nt][r] = 0.f;

    for (int kc = 0; kc < 4; ++kc) {
      // B-frags for this kc from PERSISTENT sXT (16 VGPR live)
      h8 bfr[2][2];
#pragma unroll
      for (int ks = 0; ks < 2; ++ks)
#pragma unroll
        for (int nt = 0; nt < 2; ++nt)
          bfr[ks][nt] = *(const h8*)(sXT + (tB + nt * 16) * 264 + kc * 64 +
                                     ks * 32 + 8 * g);
      // stage A tile [128 f][64 c]: linear LDS dest, swizzled global source
#pragma unroll
      for (int i = 0; i < 4; ++i) {
        const int row = r0 + i * 8 + rl;
        gll16(wqt + (long)(f0 + row) * 256 + kc * 64 + chs, sA + (r0 + i * 8) * 64);
      }
      __syncthreads();
#pragma unroll
      for (int ks = 0; ks < 2; ++ks) {
        const int kk = (ks * 32 + 8 * g) ^ kx;  // swizzled read offset
        h8 af[4];
#pragma unroll
        for (int mt = 0; mt < 4; ++mt)
          af[mt] = *(const h8*)(sA + (wr * 64 + mt * 16 + l16) * 64 + kk);
#pragma unroll
        for (int mt = 0; mt < 4; ++mt)
#pragma unroll
          for (int nt = 0; nt < 2; ++nt)
            acc[mt][nt] = MFMA32(af[mt], bfr[ks][nt], acc[mt][nt]);
      }
      __syncthreads();
    }

    // epilogue: bias + repack to sO[t][f-local] (sO aliases sA; barrier'd)
#pragma unroll
    for (int mt = 0; mt < 4; ++mt) {
      f4 bb = *(const f4*)(bqkv + f0 + wr * 64 + mt * 16 + 4 * g);
#pragma unroll
      for (int nt = 0; nt < 2; ++nt) {
        const int tl = wc * 32 + nt * 16 + l16;
#pragma unroll
        for (int r = 0; r < 4; ++r)
          sO[tl * 136 + wr * 64 + mt * 16 + 4 * g + r] =
              (_Float16)(acc[mt][nt][r] + bb[r]);
      }
    }
    __syncthreads();
    // store: per (ft,h2) -> one (qi,head): 8KB contiguous
#pragma unroll
    for (int h2 = 0; h2 < 2; ++h2) {
      const int fh = f0 + h2 * 64;
      const int qi = fh >> 8, head = (fh >> 6) & 3;
      _Float16* dst = qkv + (((long)(qi * nb + bl) * 4 + head) * 128 + hb) * 8192 +
                      (w0 + wl) * 64 + dc * 16;
      const _Float16* s = sO + wl * 136 + h2 * 64 + dc * 16;
      *(u4*)dst = *(const u4*)s;
      *(u4*)(dst + 8) = *(const u4*)(s + 8);
    }
    __syncthreads();
  }
}

// ---------------- K2: attention per (w, head, bl) ---------------- (v15-proven)
__global__ __launch_bounds__(256) void k2_attn(const _Float16* __restrict__ qkv,
                                               _Float16* __restrict__ attnout,
                                               int nb) {
  const int w = blockIdx.x, head = blockIdx.y, bl = blockIdx.z;
  const int tid = threadIdx.x;
  const int lane = tid & 63, wv = tid >> 6;
  const int g = lane >> 4, l16 = lane & 15;

  __shared__ __align__(16) char smem[(128 * 72 * 2 + 64 * 136) * 2];  // 54272 B
  _Float16* sQ = (_Float16*)smem;
  _Float16* sK = sQ + 128 * 72;
  _Float16* sVT = sK + 128 * 72;
  _Float16* sP = sQ;
  _Float16* sO = sQ;

  const long base = (((long)bl * 4 + head) * 128) * 8192 + (long)w * 64;
  const long QS = (long)nb * 4 * 128 * 8192;
  const _Float16* qg = qkv + base;
  const _Float16* kg = qkv + base + QS;
  const _Float16* vg = qkv + base + 2 * QS;

#pragma unroll
  for (int i = 0; i < 4; ++i) {
    int u = tid + 256 * i;
    int hh = u >> 3, dq = u & 7;
    *(u4*)(sQ + hh * 72 + dq * 8) = *(const u4*)(qg + (long)hh * 8192 + dq * 8);
    *(u4*)(sK + hh * 72 + dq * 8) = *(const u4*)(kg + (long)hh * 8192 + dq * 8);
  }
  {
    const int hh = tid & 127, dcv = tid >> 7;
#pragma unroll
    for (int jj = 0; jj < 4; ++jj) {
      u4 vv = *(const u4*)(vg + (long)hh * 8192 + dcv * 32 + jj * 8);
      const _Float16* pe = (const _Float16*)&vv;
#pragma unroll
      for (int e = 0; e < 8; ++e)
        sVT[(dcv * 32 + jj * 8 + e) * 136 + hh] = pe[e];
    }
  }
  __syncthreads();

  f4 accS[8][2];
  for (int i = 0; i < 8; ++i)
    for (int jt = 0; jt < 2; ++jt)
      for (int r = 0; r < 4; ++r) accS[i][jt][r] = 0.f;
#pragma unroll
  for (int ks = 0; ks < 2; ++ks) {
    const int k = ks * 32 + 8 * g;
    h8 af[8], bf[2];
#pragma unroll
    for (int i = 0; i < 8; ++i)
      af[i] = *(const h8*)(sK + (i * 16 + l16) * 72 + k);
#pragma unroll
    for (int jt = 0; jt < 2; ++jt)
      bf[jt] = *(const h8*)(sQ + (wv * 32 + jt * 16 + l16) * 72 + k);
#pragma unroll
    for (int i = 0; i < 8; ++i)
#pragma unroll
      for (int jt = 0; jt < 2; ++jt)
        accS[i][jt] = MFMA32(af[i], bf[jt], accS[i][jt]);
  }

  float rinv[2];
#pragma unroll
  for (int jt = 0; jt < 2; ++jt) {
    float m = -1e30f;
    for (int i = 0; i < 8; ++i)
      for (int r = 0; r < 4; ++r) m = fmaxf(m, accS[i][jt][r]);
    m = fmaxf(m, __shfl_xor(m, 16));
    m = fmaxf(m, __shfl_xor(m, 32));
    float s = 0.f;
    for (int i = 0; i < 8; ++i)
      for (int r = 0; r < 4; ++r) {
        float p = __expf((accS[i][jt][r] - m) * 0.125f);
        accS[i][jt][r] = p;
        s += p;
      }
    s += __shfl_xor(s, 16);
    s += __shfl_xor(s, 32);
    rinv[jt] = 1.0f / s;
  }

  __syncthreads();
#pragma unroll
  for (int jt = 0; jt < 2; ++jt) {
    const int hq = wv * 32 + jt * 16 + l16;
#pragma unroll
    for (int i = 0; i < 8; ++i) {
      h4 pv;
      pv[0] = (_Float16)accS[i][jt][0];
      pv[1] = (_Float16)accS[i][jt][1];
      pv[2] = (_Float16)accS[i][jt][2];
      pv[3] = (_Float16)accS[i][jt][3];
      *(h4*)(sP + hq * 136 + i * 16 + 4 * g) = pv;
    }
  }
  __syncthreads();

  f4 accO[4][2];
  for (int mt = 0; mt < 4; ++mt)
    for (int jt = 0; jt < 2; ++jt)
      for (int r = 0; r < 4; ++r) accO[mt][jt][r] = 0.f;
#pragma unroll
  for (int i2 = 0; i2 < 4; ++i2) {
    const int k = i2 * 32 + 8 * g;
    h8 av[4], pb[2];
#pragma unroll
    for (int mt = 0; mt < 4; ++mt)
      av[mt] = *(const h8*)(sVT + (mt * 16 + l16) * 136 + k);
#pragma unroll
    for (int jt = 0; jt < 2; ++jt)
      pb[jt] = *(const h8*)(sP + (wv * 32 + jt * 16 + l16) * 136 + k);
#pragma unroll
    for (int mt = 0; mt < 4; ++mt)
#pragma unroll
      for (int jt = 0; jt < 2; ++jt)
        accO[mt][jt] = MFMA32(av[mt], pb[jt], accO[mt][jt]);
  }

  __syncthreads();
#pragma unroll
  for (int mt = 0; mt < 4; ++mt)
#pragma unroll
    for (int jt = 0; jt < 2; ++jt)
#pragma unroll
      for (int r = 0; r < 4; ++r)
        sO[(wv * 32 + jt * 16 + l16) * 72 + mt * 16 + 4 * g + r] =
            (_Float16)(accO[mt][jt][r] * rinv[jt]);
  __syncthreads();

  const int hh = tid >> 1, d0 = (tid & 1) * 32;
  const _Float16* s = sO + hh * 72 + d0;
  _Float16* dst = attnout + ((long)bl * 16384 + hh * 128 + w) * 256 + head * 64 + d0;
#pragma unroll
  for (int e = 0; e < 4; ++e)
    *(u4*)(dst + e * 8) = *(const u4*)(s + e * 8);
}

// ---------------- K3: out[b][co][t] = Wproj^T[co][c]*attnout[t][c]+bproj --------
// (v14-proven: swizzled A/B staging + reads)
__global__ __launch_bounds__(256, 4) void k3_proj(const _Float16* __restrict__ attnout,
                                                  const _Float16* __restrict__ wpt,
                                                  const float* __restrict__ bproj,
                                                  float* __restrict__ out,
                                                  int b_base, int nb) {
  const int ct = blockIdx.x, tt = blockIdx.y, bl = blockIdx.z;
  const int b = b_base + bl;
  const int tid = threadIdx.x;
  const int lane = tid & 63, wv = tid >> 6;
  const int g = lane >> 4, l16 = lane & 15;
  const int wr = wv >> 1, wc = wv & 1;
  const int co0 = ct * 128;
  const long t0 = (long)tt * 128;

  __shared__ __align__(16) char smem[33792];
  _Float16* sA = (_Float16*)smem;   // [128 co][64]
  _Float16* sB = sA + 128 * 64;     // [128 t][64]
  float* sOut = (float*)smem;       // reuse: [64][132] f32

  f4 acc[4][4];
#pragma unroll
  for (int mt = 0; mt < 4; ++mt)
#pragma unroll
    for (int nt = 0; nt < 4; ++nt)
#pragma unroll
      for (int r = 0; r < 4; ++r) acc[mt][nt][r] = 0.f;

  const _Float16* Ab = wpt + (long)co0 * 256;
  const _Float16* Bb = attnout + ((long)bl * 16384 + t0) * 256;
  const int r0 = wv * 32;
  const int rl = lane >> 3;
  const int chs = ((lane & 7) ^ rl) * 8;  // swizzled source chunk
  const int kx = (l16 & 7) * 8;           // read XOR

  for (int kc = 0; kc < 4; ++kc) {
    const int c0 = kc * 64;
#pragma unroll
    for (int i = 0; i < 4; ++i) {
      const int row = r0 + i * 8 + rl;
      gll16(Ab + (long)row * 256 + c0 + chs, sA + (r0 + i * 8) * 64);
      gll16(Bb + (long)row * 256 + c0 + chs, sB + (r0 + i * 8) * 64);
    }
    __syncthreads();
#pragma unroll
    for (int ks = 0; ks < 2; ++ks) {
      const int kk = (ks * 32 + 8 * g) ^ kx;
      h8 af[4], bf[4];
#pragma unroll
      for (int mt = 0; mt < 4; ++mt)
        af[mt] = *(const h8*)(sA + (wr * 64 + mt * 16 + l16) * 64 + kk);
#pragma unroll
      for (int nt = 0; nt < 4; ++nt)
        bf[nt] = *(const h8*)(sB + (wc * 64 + nt * 16 + l16) * 64 + kk);
#pragma unroll
      for (int mt = 0; mt < 4; ++mt)
#pragma unroll
        for (int nt = 0; nt < 4; ++nt)
          acc[mt][nt] = MFMA32(af[mt], bf[nt], acc[mt][nt]);
    }
    __syncthreads();
  }

#pragma unroll
  for (int h2 = 0; h2 < 2; ++h2) {
    if (h2) __syncthreads();
    if (wr == h2) {
#pragma unroll
      for (int mt = 0; mt < 4; ++mt) {
        f4 bb = *(const f4*)(bproj + co0 + h2 * 64 + mt * 16 + 4 * g);
#pragma unroll
        for (int nt = 0; nt < 4; ++nt)
#pragma unroll
          for (int r = 0; r < 4; ++r)
            sOut[(mt * 16 + 4 * g + r) * 132 + wc * 64 + nt * 16 + l16] =
                acc[mt][nt][r] + bb[r];
      }
    }
    __syncthreads();
    const int row = tid >> 2, seg = (tid & 3) * 32;
    const float* s = sOut + row * 132 + seg;
    float* dst = out + ((long)b * 256 + co0 + h2 * 64 + row) * 16384 + t0 + seg;
#pragma unroll
    for (int e = 0; e < 8; ++e)
      *(f4*)(dst + e * 4) = *(const f4*)(s + e * 4);
  }
}

// ---------------- launch ----------------
extern "C" void kernel_launch(void* const* d_in, const int* in_sizes, int n_in,
                              void* d_out, int out_size, void* d_ws, size_t ws_size,
                              hipStream_t stream) {
  const float* x = (const float*)d_in[0];
  const float* Wqkv = (const float*)d_in[1];
  const float* bqkv = (const float*)d_in[2];
  const float* Wproj = (const float*)d_in[3];
  const float* bproj = (const float*)d_in[4];
  float* out = (float*)d_out;

  char* ws = (char*)d_ws;
  // Layout: [wqt 384K][wpt 128K][qkv nb*24Mi][attnout nb*8Mi]
  const long WQT = 393216L, WPT = 131072L;
  const long PER_B = 25165824L + 8388608L;
  long nb_l = ((long)ws_size - (WQT + WPT)) / PER_B;
  int nb = nb_l < 1 ? 1 : (nb_l > 8 ? 8 : (int)nb_l);

  _Float16* wqt = (_Float16*)ws;
  _Float16* wpt = (_Float16*)(ws + WQT);
  _Float16* qkv = (_Float16*)(ws + WQT + WPT);
  _Float16* attnout = (_Float16*)(ws + WQT + WPT + (long)nb * 25165824L);

  prep_w<<<1024, 256, 0, stream>>>(Wqkv, Wproj, wqt, wpt);

  for (int b0 = 0; b0 < 8; b0 += nb) {
    int nbv = (8 - b0 < nb) ? (8 - b0) : nb;
    k1f<<<nbv * 256, 256, 0, stream>>>(x, wqt, bqkv, qkv, b0, nbv);
    k2_attn<<<dim3(128, 4, nbv), 256, 0, stream>>>(qkv, attnout, nbv);
    k3_proj<<<dim3(2, 128, nbv), 256, 0, stream>>>(attnout, wpt, bproj, out, b0, nbv);
  }
}